// Round 1
// baseline (11.756 us; speedup 1.0000x reference)
//
#include <hip/hip_runtime.h>
#include <math.h>

#define NH 32
#define NL 8
#define NF 128

__device__ __forceinline__ float dot_v4(const float* __restrict__ w,
                                        const float* __restrict__ s, int n4) {
    const float4* w4 = (const float4*)w;
    const float4* s4 = (const float4*)s;
    float acc = 0.f;
#pragma unroll 8
    for (int i = 0; i < n4; ++i) {
        float4 a = w4[i];
        float4 b = s4[i];
        acc = fmaf(a.x, b.x, acc);
        acc = fmaf(a.y, b.y, acc);
        acc = fmaf(a.z, b.z, acc);
        acc = fmaf(a.w, b.w, acc);
    }
    return acc;
}

__device__ __forceinline__ float sigmoidf_(float x) {
    return 1.0f / (1.0f + __expf(-x));
}

__device__ __forceinline__ float preluf_(float x, float a) {
    return x >= 0.0f ? x : a * x;
}

__global__ void __launch_bounds__(128)
omni_anomaly_kernel(const float* __restrict__ x,
                    const float* __restrict__ hidden,
                    const float* __restrict__ eps,
                    const float* __restrict__ w_ih0, const float* __restrict__ w_hh0,
                    const float* __restrict__ b_ih0, const float* __restrict__ b_hh0,
                    const float* __restrict__ w_ih1, const float* __restrict__ w_hh1,
                    const float* __restrict__ b_ih1, const float* __restrict__ b_hh1,
                    const float* __restrict__ enc_w1, const float* __restrict__ enc_b1,
                    const float* __restrict__ enc_a1,
                    const float* __restrict__ enc_w2, const float* __restrict__ enc_b2,
                    const float* __restrict__ enc_a2,
                    const float* __restrict__ enc_w3, const float* __restrict__ enc_b3,
                    const float* __restrict__ dec_w1, const float* __restrict__ dec_b1,
                    const float* __restrict__ dec_a1,
                    const float* __restrict__ dec_w2, const float* __restrict__ dec_b2,
                    const float* __restrict__ dec_a2,
                    const float* __restrict__ dec_w3, const float* __restrict__ dec_b3,
                    float* __restrict__ out) {
    __shared__ __align__(16) float sx[NF];
    __shared__ __align__(16) float sh0[NH];
    __shared__ __align__(16) float sh1[NH];
    __shared__ __align__(16) float gi[3 * NH];
    __shared__ __align__(16) float gh[3 * NH];
    __shared__ __align__(16) float h0n[NH];
    __shared__ __align__(16) float h1n[NH];
    __shared__ __align__(16) float e_buf[NH];
    __shared__ __align__(16) float e2_buf[NH];
    __shared__ __align__(16) float z_buf[NL];
    __shared__ __align__(16) float d1_buf[NH];
    __shared__ __align__(16) float d2_buf[NH];

    const int tid = threadIdx.x;

    // ---- stage in x and hidden states ----
    if (tid < NF) sx[tid] = x[tid];
    if (tid < NH) {
        sh0[tid] = hidden[tid];        // hidden[0,0,:]
        sh1[tid] = hidden[NH + tid];   // hidden[1,0,:]
    }
    __syncthreads();

    // ---- GRU cell 0: gi = w_ih0 @ x + b_ih0 ; gh = w_hh0 @ h0 + b_hh0 ----
    if (tid < 3 * NH) {
        gi[tid] = dot_v4(w_ih0 + tid * NF, sx, NF / 4) + b_ih0[tid];
        gh[tid] = dot_v4(w_hh0 + tid * NH, sh0, NH / 4) + b_hh0[tid];
    }
    __syncthreads();
    if (tid < NH) {
        float r = sigmoidf_(gi[tid] + gh[tid]);
        float z = sigmoidf_(gi[NH + tid] + gh[NH + tid]);
        float n = tanhf(gi[2 * NH + tid] + r * gh[2 * NH + tid]);
        float h = (1.0f - z) * n + z * sh0[tid];
        h0n[tid] = h;
        out[NF + 2 * NL + tid] = h;  // hidden_new[0,0,:]
    }
    __syncthreads();

    // ---- GRU cell 1 ----
    if (tid < 3 * NH) {
        gi[tid] = dot_v4(w_ih1 + tid * NH, h0n, NH / 4) + b_ih1[tid];
        gh[tid] = dot_v4(w_hh1 + tid * NH, sh1, NH / 4) + b_hh1[tid];
    }
    __syncthreads();
    if (tid < NH) {
        float r = sigmoidf_(gi[tid] + gh[tid]);
        float z = sigmoidf_(gi[NH + tid] + gh[NH + tid]);
        float n = tanhf(gi[2 * NH + tid] + r * gh[2 * NH + tid]);
        float h = (1.0f - z) * n + z * sh1[tid];
        h1n[tid] = h;
        out[NF + 2 * NL + NH + tid] = h;  // hidden_new[1,0,:]
    }
    __syncthreads();

    // ---- encoder layer 1: prelu(enc_w1 @ h1 + enc_b1, a1) ----
    if (tid < NH) {
        float v = dot_v4(enc_w1 + tid * NH, h1n, NH / 4) + enc_b1[tid];
        e_buf[tid] = preluf_(v, enc_a1[0]);
    }
    __syncthreads();

    // ---- encoder layer 2 ----
    if (tid < NH) {
        float v = dot_v4(enc_w2 + tid * NH, e_buf, NH / 4) + enc_b2[tid];
        e2_buf[tid] = preluf_(v, enc_a2[0]);
    }
    __syncthreads();

    // ---- encoder layer 3 -> mu, logvar; reparameterize ----
    if (tid < 2 * NL) {
        float v = dot_v4(enc_w3 + tid * NH, e2_buf, NH / 4) + enc_b3[tid];
        out[NF + tid] = v;  // mu at [NF, NF+NL), logvar at [NF+NL, NF+2NL)
        if (tid < NL) {
            // need logvar too; recompute partner row for z (cheap: 32 MACs)
            float lv = dot_v4(enc_w3 + (NL + tid) * NH, e2_buf, NH / 4) + enc_b3[NL + tid];
            float std_ = __expf(0.5f * lv);
            z_buf[tid] = v + eps[tid] * std_;
        }
    }
    __syncthreads();

    // ---- decoder layer 1: prelu(dec_w1 @ z + dec_b1, da1), w is (32,8) ----
    if (tid < NH) {
        float v = dot_v4(dec_w1 + tid * NL, z_buf, NL / 4) + dec_b1[tid];
        d1_buf[tid] = preluf_(v, dec_a1[0]);
    }
    __syncthreads();

    // ---- decoder layer 2 ----
    if (tid < NH) {
        float v = dot_v4(dec_w2 + tid * NH, d1_buf, NH / 4) + dec_b2[tid];
        d2_buf[tid] = preluf_(v, dec_a2[0]);
    }
    __syncthreads();

    // ---- decoder layer 3: sigmoid(dec_w3 @ d2 + dec_b3), 128 rows ----
    if (tid < NF) {
        float v = dot_v4(dec_w3 + tid * NH, d2_buf, NH / 4) + dec_b3[tid];
        out[tid] = sigmoidf_(v);
    }
}

extern "C" void kernel_launch(void* const* d_in, const int* in_sizes, int n_in,
                              void* d_out, int out_size, void* d_ws, size_t ws_size,
                              hipStream_t stream) {
    const float* x      = (const float*)d_in[0];
    const float* hidden = (const float*)d_in[1];
    const float* eps    = (const float*)d_in[2];
    const float* w_ih0  = (const float*)d_in[3];
    const float* w_hh0  = (const float*)d_in[4];
    const float* b_ih0  = (const float*)d_in[5];
    const float* b_hh0  = (const float*)d_in[6];
    const float* w_ih1  = (const float*)d_in[7];
    const float* w_hh1  = (const float*)d_in[8];
    const float* b_ih1  = (const float*)d_in[9];
    const float* b_hh1  = (const float*)d_in[10];
    const float* enc_w1 = (const float*)d_in[11];
    const float* enc_b1 = (const float*)d_in[12];
    const float* enc_a1 = (const float*)d_in[13];
    const float* enc_w2 = (const float*)d_in[14];
    const float* enc_b2 = (const float*)d_in[15];
    const float* enc_a2 = (const float*)d_in[16];
    const float* enc_w3 = (const float*)d_in[17];
    const float* enc_b3 = (const float*)d_in[18];
    const float* dec_w1 = (const float*)d_in[19];
    const float* dec_b1 = (const float*)d_in[20];
    const float* dec_a1 = (const float*)d_in[21];
    const float* dec_w2 = (const float*)d_in[22];
    const float* dec_b2 = (const float*)d_in[23];
    const float* dec_a2 = (const float*)d_in[24];
    const float* dec_w3 = (const float*)d_in[25];
    const float* dec_b3 = (const float*)d_in[26];
    float* out = (float*)d_out;

    omni_anomaly_kernel<<<1, 128, 0, stream>>>(
        x, hidden, eps,
        w_ih0, w_hh0, b_ih0, b_hh0,
        w_ih1, w_hh1, b_ih1, b_hh1,
        enc_w1, enc_b1, enc_a1,
        enc_w2, enc_b2, enc_a2,
        enc_w3, enc_b3,
        dec_w1, dec_b1, dec_a1,
        dec_w2, dec_b2, dec_a2,
        dec_w3, dec_b3,
        out);
}